// Round 10
// baseline (706.049 us; speedup 1.0000x reference)
//
#include <hip/hip_runtime.h>
#include <math.h>

#define NPG 100
#define KTOP 60
#define DLAT 97
#define NC 250          // coarse buckets (8 graphs = 800 nodes each)
#define NODESC 800      // nodes per coarse bucket
#define NBLKA 256       // binning blocks (fewer -> longer per-bucket runs -> full-line writes)

static __device__ __forceinline__ float dot4(float4 a, float4 b){
  return a.x*b.x + a.y*b.y + a.z*b.z + a.w*b.w;
}

// ---------------- prep: two-level atomic-free CSR build ----------------
// histT[c*NBLKA + blk] (transposed so colscanA reads coalesced)
__global__ __launch_bounds__(256) void k_histA(const int* __restrict__ dst, int* __restrict__ histT,
    int E, int cpb){
  __shared__ int h[NC];
  int blk = blockIdx.x, tid = threadIdx.x;
  if(tid < NC) h[tid] = 0;
  __syncthreads();
  int e0 = blk*cpb, e1 = min(e0+cpb, E);
  for(int e=e0+tid; e<e1; e+=256) atomicAdd(&h[dst[e]/NODESC], 1);
  __syncthreads();
  if(tid < NC) histT[tid*NBLKA + blk] = h[tid];
}

// block per coarse bucket: exclusive scan over binning blocks (coalesced read/write)
__global__ __launch_bounds__(NBLKA) void k_colscanA(const int* __restrict__ histT,
    int* __restrict__ prefA, int* __restrict__ totalA){
  __shared__ int s[NBLKA];
  int c = blockIdx.x, t = threadIdx.x;
  int v = histT[c*NBLKA + t];
  s[t] = v;
  __syncthreads();
  for(int off=1; off<NBLKA; off<<=1){
    int u = (t >= off) ? s[t-off] : 0;
    __syncthreads();
    s[t] += u;
    __syncthreads();
  }
  prefA[c*NBLKA + t] = s[t] - v;
  if(t == NBLKA-1) totalA[c] = s[t];
}

__global__ __launch_bounds__(256) void k_bscanA(const int* __restrict__ totalA, int* __restrict__ cbase){
  __shared__ int s[256];
  int t = threadIdx.x;
  int v = (t < NC) ? totalA[t] : 0;
  s[t] = v;
  __syncthreads();
  for(int off=1; off<256; off<<=1){
    int u = (t >= off) ? s[t-off] : 0;
    __syncthreads();
    s[t] += u;
    __syncthreads();
  }
  if(t < NC) cbase[t] = s[t] - v;
  if(t == 255) cbase[NC] = s[255];
}

// coarse scatter: packed edge x = src | (dst%NODESC)<<18, y = bits of ew
__global__ __launch_bounds__(256) void k_scatterA(const int* __restrict__ src, const int* __restrict__ dst,
    const float* __restrict__ ew, const int* __restrict__ prefA, const int* __restrict__ cbase,
    int2* __restrict__ ebufA, int E, int cpb){
  __shared__ int cur[NC];
  int blk = blockIdx.x, tid = threadIdx.x;
  if(tid < NC) cur[tid] = prefA[tid*NBLKA + blk] + cbase[tid];
  __syncthreads();
  int e0 = blk*cpb, e1 = min(e0+cpb, E);
  for(int e=e0+tid; e<e1; e+=256){
    int d = dst[e];
    int c = d/NODESC;
    int dm = d - c*NODESC;
    int pos = atomicAdd(&cur[c], 1);          // LDS atomic
    ebufA[pos] = make_int2(src[e] | (dm<<18), __float_as_int(ew[e]));
  }
}

// block per coarse bucket: degree -> dis, row starts, scatter to final CSR
__global__ __launch_bounds__(1024) void k_bucket8(const int2* __restrict__ ebufA, const int* __restrict__ cbase,
    float* __restrict__ dis, int* __restrict__ rs, int2* __restrict__ csr, int N){
  __shared__ float degw[NODESC];
  __shared__ int cnt[NODESC];
  __shared__ int cur[NODESC];
  __shared__ int sc[1024];
  int c = blockIdx.x, tid = threadIdx.x;
  int n0 = c*NODESC;
  if(tid < NODESC){ degw[tid] = 0.f; cnt[tid] = 0; }
  __syncthreads();
  int e0 = cbase[c], e1 = cbase[c+1];
  for(int e=e0+tid; e<e1; e+=1024){
    int2 t = ebufA[e];
    int ld = ((unsigned)t.x)>>18;
    atomicAdd(&cnt[ld], 1);
    atomicAdd(&degw[ld], __int_as_float(t.y));
  }
  __syncthreads();
  if(tid < NODESC) dis[n0+tid] = rsqrtf(degw[tid] + 1.0f);
  sc[tid] = (tid < NODESC) ? cnt[tid] : 0;
  __syncthreads();
  for(int off=1; off<1024; off<<=1){
    int u = (tid >= off) ? sc[tid-off] : 0;
    __syncthreads();
    sc[tid] += u;
    __syncthreads();
  }
  if(tid < NODESC){
    int st = e0 + sc[tid] - cnt[tid];
    cur[tid] = st;
    rs[n0+tid] = st;
  }
  if(c == NC-1 && tid == 0) rs[N] = e1;
  __syncthreads();
  for(int e=e0+tid; e<e1; e+=1024){
    int2 t = ebufA[e];
    int ld = ((unsigned)t.x)>>18;
    int pos = atomicAdd(&cur[ld], 1);
    csr[pos] = make_int2((t.x & 0x3FFFF) << 7, t.y);   // src as BYTE offset (src*128)
  }
}

// ---------------- GEMMs (row-major out, pre-scaled by dis[n]) ----------------
__global__ __launch_bounds__(256) void k_gemm1(const int* __restrict__ wI, const int* __restrict__ z1I,
   const int* __restrict__ z2I,
   const float* __restrict__ embw, const float* __restrict__ embz1, const float* __restrict__ embz2,
   const float* __restrict__ W0, const float* __restrict__ dis, float* __restrict__ gx, int N){
  __shared__ __align__(16) float X[128][97];
  __shared__ __align__(16) float Ws[96*32];
  __shared__ int iw[128], i1[128], i2[128];
  int tid = threadIdx.x;
  int g0 = blockIdx.x*128;
  for(int i=tid;i<768;i+=256) ((float4*)Ws)[i] = ((const float4*)W0)[i];
  if(tid < 128){
    int gn = g0 + tid;
    bool ok = gn < N;
    iw[tid] = ok ? wI[gn]  : 0;
    i1[tid] = ok ? z1I[gn] : 0;
    i2[tid] = ok ? z2I[gn] : 0;
  }
  __syncthreads();
  for(int r=0;r<48;r++){
    int flat = r*256 + tid;
    int n = flat/96, c = flat - n*96;
    int gn = g0 + n;
    float val = 0.f;
    if(gn < N){
      if(c < 32)      val = embw [iw[n]*32 + c];
      else if(c < 64) val = embz1[i1[n]*32 + (c-32)];
      else            val = embz2[i2[n]*32 + (c-64)];
    }
    X[n][c] = val;
  }
  __syncthreads();
  int ng = tid>>3, chg = tid&7;
  float4 acc[4];
  #pragma unroll
  for(int j=0;j<4;j++) acc[j] = make_float4(0.f,0.f,0.f,0.f);
  #pragma unroll 4
  for(int i=0;i<96;i++){
    float4 wv = *(const float4*)&Ws[i*32 + chg*4];
    #pragma unroll
    for(int j=0;j<4;j++){
      float xv = X[ng*4+j][i];
      acc[j].x += xv*wv.x; acc[j].y += xv*wv.y; acc[j].z += xv*wv.z; acc[j].w += xv*wv.w;
    }
  }
  #pragma unroll
  for(int j=0;j<4;j++){
    int gn = g0 + ng*4 + j;
    if(gn < N){
      float dv = dis[gn];
      acc[j].x *= dv; acc[j].y *= dv; acc[j].z *= dv; acc[j].w *= dv;
      *(float4*)&gx[(size_t)gn*32 + chg*4] = acc[j];
    }
  }
}

__global__ __launch_bounds__(256) void k_gemm32(const float* __restrict__ xin, const float* __restrict__ W,
    const float* __restrict__ dis, float* __restrict__ gx, int N){
  __shared__ __align__(16) float X[128][33];
  __shared__ __align__(16) float Ws[32*32];
  int tid = threadIdx.x;
  int g0 = blockIdx.x*128;
  ((float4*)Ws)[tid] = ((const float4*)W)[tid];
  for(int r=0;r<4;r++){
    int f = r*256 + tid;
    int n = f>>3, c4 = f&7;
    int gn = g0 + n;
    float4 v = (gn < N) ? ((const float4*)(xin + (size_t)gn*32))[c4] : make_float4(0,0,0,0);
    float* xr = &X[n][c4*4];
    xr[0]=v.x; xr[1]=v.y; xr[2]=v.z; xr[3]=v.w;
  }
  __syncthreads();
  int ng = tid>>3, chg = tid&7;
  float4 acc[4];
  #pragma unroll
  for(int j=0;j<4;j++) acc[j] = make_float4(0.f,0.f,0.f,0.f);
  #pragma unroll 4
  for(int i=0;i<32;i++){
    float4 wv = *(const float4*)&Ws[i*32 + chg*4];
    #pragma unroll
    for(int j=0;j<4;j++){
      float xv = X[ng*4+j][i];
      acc[j].x += xv*wv.x; acc[j].y += xv*wv.y; acc[j].z += xv*wv.z; acc[j].w += xv*wv.w;
    }
  }
  #pragma unroll
  for(int j=0;j<4;j++){
    int gn = g0 + ng*4 + j;
    if(gn < N){
      float dv = dis[gn];
      acc[j].x *= dv; acc[j].y *= dv; acc[j].z *= dv; acc[j].w *= dv;
      *(float4*)&gx[(size_t)gn*32 + chg*4] = acc[j];
    }
  }
}

// ---------------- aggregation: wave/node, 8 edge-slots x 8 ch-groups (R6 simple form) ----------------
__global__ __launch_bounds__(256) void k_agg32(const float* __restrict__ g,
   const float* __restrict__ dis, const int* __restrict__ rs, const int2* __restrict__ csr,
   const float* __restrict__ bias, float* __restrict__ hout, int N){
  int wave = threadIdx.x >> 6;
  int lane = threadIdx.x & 63;
  int es = lane >> 3;
  int cg = lane & 7;
  int n = blockIdx.x*4 + wave;
  if(n >= N) return;
  int e0 = rs[n], e1 = rs[n+1];
  int deg = e1 - e0;
  int full = deg >> 3, rem = deg & 7;
  const char* gb = (const char*)g;
  int cgo = cg*16;
  float4 acc = make_float4(0.f,0.f,0.f,0.f);
  int idx = e0 + es;
  for(int it=0; it<full; ++it){
    int2 p = csr[idx];
    float w = __int_as_float(p.y);
    float4 v = *(const float4*)(gb + (p.x + cgo));
    acc.x += w*v.x; acc.y += w*v.y; acc.z += w*v.z; acc.w += w*v.w;
    idx += 8;
  }
  if(es < rem){
    int2 p = csr[idx];
    float w = __int_as_float(p.y);
    float4 v = *(const float4*)(gb + (p.x + cgo));
    acc.x += w*v.x; acc.y += w*v.y; acc.z += w*v.z; acc.w += w*v.w;
  }
  #pragma unroll
  for(int off=8; off<64; off<<=1){
    acc.x += __shfl_xor(acc.x, off);
    acc.y += __shfl_xor(acc.y, off);
    acc.z += __shfl_xor(acc.z, off);
    acc.w += __shfl_xor(acc.w, off);
  }
  float4 self = ((const float4*)(g + (size_t)n*32))[cg];
  float dn = dis[n];
  float4 bv = ((const float4*)bias)[cg];
  if(es == 0){
    float4 o;
    o.x = tanhf(dn*(acc.x + self.x) + bv.x);
    o.y = tanhf(dn*(acc.y + self.y) + bv.y);
    o.z = tanhf(dn*(acc.z + self.z) + bv.z);
    o.w = tanhf(dn*(acc.w + self.w) + bv.w);
    ((float4*)(hout + (size_t)n*32))[cg] = o;
  }
}

// layer-3 variant: also emits gv[n] = (h3 . W3) * dis[n]  (fused gemmv)
__global__ __launch_bounds__(256) void k_agg32v(const float* __restrict__ g,
   const float* __restrict__ dis, const int* __restrict__ rs, const int2* __restrict__ csr,
   const float* __restrict__ bias, const float* __restrict__ W3,
   float* __restrict__ hout, float* __restrict__ gv, int N){
  int wave = threadIdx.x >> 6;
  int lane = threadIdx.x & 63;
  int es = lane >> 3;
  int cg = lane & 7;
  int n = blockIdx.x*4 + wave;
  if(n >= N) return;
  int e0 = rs[n], e1 = rs[n+1];
  int deg = e1 - e0;
  int full = deg >> 3, rem = deg & 7;
  const char* gb = (const char*)g;
  int cgo = cg*16;
  float4 acc = make_float4(0.f,0.f,0.f,0.f);
  int idx = e0 + es;
  for(int it=0; it<full; ++it){
    int2 p = csr[idx];
    float w = __int_as_float(p.y);
    float4 v = *(const float4*)(gb + (p.x + cgo));
    acc.x += w*v.x; acc.y += w*v.y; acc.z += w*v.z; acc.w += w*v.w;
    idx += 8;
  }
  if(es < rem){
    int2 p = csr[idx];
    float w = __int_as_float(p.y);
    float4 v = *(const float4*)(gb + (p.x + cgo));
    acc.x += w*v.x; acc.y += w*v.y; acc.z += w*v.z; acc.w += w*v.w;
  }
  #pragma unroll
  for(int off=8; off<64; off<<=1){
    acc.x += __shfl_xor(acc.x, off);
    acc.y += __shfl_xor(acc.y, off);
    acc.z += __shfl_xor(acc.z, off);
    acc.w += __shfl_xor(acc.w, off);
  }
  float4 self = ((const float4*)(g + (size_t)n*32))[cg];
  float dn = dis[n];
  float4 bv = ((const float4*)bias)[cg];
  if(es == 0){
    float4 o;
    o.x = tanhf(dn*(acc.x + self.x) + bv.x);
    o.y = tanhf(dn*(acc.y + self.y) + bv.y);
    o.z = tanhf(dn*(acc.z + self.z) + bv.z);
    o.w = tanhf(dn*(acc.w + self.w) + bv.w);
    ((float4*)(hout + (size_t)n*32))[cg] = o;
    float4 w3v = *(const float4*)&W3[cg*4];
    float s = dot4(o, w3v);
    s += __shfl_xor(s, 1);
    s += __shfl_xor(s, 2);
    s += __shfl_xor(s, 4);
    if(cg == 0) gv[n] = s*dn;
  }
}

// ---------------- kA: fused agg1 + sort + gather + conv1 + maxpool -> t2G[B][16][30] ----------------
__global__ __launch_bounds__(256) void k_sortpool(const float* __restrict__ gv,
  const float* __restrict__ dis, const int* __restrict__ rs, const int2* __restrict__ csr,
  const float* __restrict__ b3,
  const float* __restrict__ h1,const float* __restrict__ h2,const float* __restrict__ h3,
  const float* __restrict__ c1W,const float* __restrict__ c1b,
  float* __restrict__ t2G, int N){
  __shared__ float v[128];
  __shared__ int ord[KTOP];
  __shared__ __align__(16) float xk[KTOP][100];
  __shared__ __align__(16) float c1Ws[16*100];
  __shared__ __align__(16) float t2s[480];
  int b = blockIdx.x, tid = threadIdx.x;
  int g0 = b*NPG;
  for(int i=tid;i<16*97;i+=256){ int o=i/97, d=i-o*97; c1Ws[o*100+d]=c1W[i]; }
  // fused agg1: h4 for this graph's 100 nodes (gv is globally complete)
  if(tid < 100){
    int n = g0 + tid;
    float acc = gv[n];
    int e0 = rs[n], e1 = rs[n+1];
    for(int e=e0;e<e1;e++){
      int2 p = csr[e];
      acc += __int_as_float(p.y)*gv[((unsigned)p.x)>>7];
    }
    v[tid] = tanhf(dis[n]*acc + b3[0]);
  }
  __syncthreads();
  // stable descending rank == argsort(-v) stable
  if(tid < 100){
    float vi = v[tid];
    int rank = 0;
    for(int j=0;j<100;j++){
      float vj = v[j];
      rank += (vj > vi) || (vj == vi && j < tid);
    }
    if(rank < KTOP) ord[rank] = tid;
  }
  __syncthreads();
  for(int idx=tid; idx<KTOP*DLAT; idx+=256){
    int k = idx/DLAT, d = idx - k*DLAT;
    int nk = ord[k];
    float val;
    if(d < 96){
      const float* hsrc = (d<32) ? h1 : (d<64) ? h2 : h3;
      val = hsrc[(size_t)(g0+nk)*32 + (d&31)];
    } else val = v[nk];
    xk[k][d] = val;
  }
  __syncthreads();
  {
    int og = tid & 7, j = tid >> 3;
    if(j < 30){
      int k0 = 2*j, k1 = 2*j+1;
      float a00=0.f, a01=0.f, a10=0.f, a11=0.f;
      for(int d=0; d<96; d+=4){
        float4 w0 = *(const float4*)&c1Ws[og*100 + d];
        float4 w1 = *(const float4*)&c1Ws[(og+8)*100 + d];
        float4 x0 = *(const float4*)&xk[k0][d];
        float4 x1 = *(const float4*)&xk[k1][d];
        a00 += dot4(x0, w0); a01 += dot4(x1, w0);
        a10 += dot4(x0, w1); a11 += dot4(x1, w1);
      }
      {
        float w0 = c1Ws[og*100 + 96], w1 = c1Ws[(og+8)*100 + 96];
        float x0 = xk[k0][96], x1 = xk[k1][96];
        a00 += x0*w0; a01 += x1*w0;
        a10 += x0*w1; a11 += x1*w1;
      }
      float b0v = c1b[og], b1v = c1b[og+8];
      float r0 = fmaxf(fmaxf(a00+b0v,0.f), fmaxf(a01+b0v,0.f));
      float r1 = fmaxf(fmaxf(a10+b1v,0.f), fmaxf(a11+b1v,0.f));
      t2s[og*30 + j] = r0;
      t2s[(og+8)*30 + j] = r1;
    }
  }
  __syncthreads();
  if(tid < 120) ((float4*)&t2G[(size_t)b*480])[tid] = ((const float4*)t2s)[tid];
}

// ---------------- kB: conv2 + l1 + l2, 8 graphs per block ----------------
__global__ __launch_bounds__(256) void k_tail(const float* __restrict__ t2G,
  const float* __restrict__ c2W,const float* __restrict__ c2b,
  const float* __restrict__ l1W,const float* __restrict__ l1b,
  const float* __restrict__ l2W,const float* __restrict__ l2b,
  float* __restrict__ out){
  __shared__ __align__(16) float t2s[8*480];
  __shared__ __align__(16) float c2Ws[2560];
  __shared__ __align__(16) float flat[8][832];
  __shared__ __align__(16) float o1s[8][128];
  int bG = blockIdx.x, tid = threadIdx.x;
  for(int i=tid; i<960; i+=256) ((float4*)t2s)[i] = ((const float4*)(t2G + (size_t)bG*8*480))[i];
  for(int i=tid; i<640; i+=256) ((float4*)c2Ws)[i] = ((const float4*)c2W)[i];
  __syncthreads();
  {
    int g = tid >> 5, oc = tid & 31;
    float acc[26];
    #pragma unroll
    for(int p=0;p<26;p++) acc[p]=0.f;
    for(int ic=0; ic<16; ic++){
      const float* trow = &t2s[g*480 + ic*30];
      float t[30];
      #pragma unroll
      for(int p=0;p<30;p++) t[p] = trow[p];
      const float* wr = &c2Ws[(oc*16 + ic)*5];
      float w0=wr[0], w1=wr[1], w2=wr[2], w3=wr[3], w4=wr[4];
      #pragma unroll
      for(int p=0;p<26;p++)
        acc[p] += t[p]*w0 + t[p+1]*w1 + t[p+2]*w2 + t[p+3]*w3 + t[p+4]*w4;
    }
    float bb = c2b[oc];
    #pragma unroll
    for(int p=0;p<26;p++) flat[g][oc*26+p] = fmaxf(acc[p]+bb, 0.f);
  }
  __syncthreads();
  {
    int j = tid & 127, gq = tid >> 7;
    float acc0=0.f, acc1=0.f, acc2=0.f, acc3=0.f;
    const float* f0 = flat[gq*4+0];
    const float* f1 = flat[gq*4+1];
    const float* f2 = flat[gq*4+2];
    const float* f3 = flat[gq*4+3];
    for(int i4=0; i4<208; i4++){
      int i = i4*4;
      float w0 = l1W[(size_t)i*128 + j];
      float w1 = l1W[(size_t)(i+1)*128 + j];
      float w2 = l1W[(size_t)(i+2)*128 + j];
      float w3 = l1W[(size_t)(i+3)*128 + j];
      float4 a0 = *(const float4*)&f0[i];
      float4 a1 = *(const float4*)&f1[i];
      float4 a2 = *(const float4*)&f2[i];
      float4 a3 = *(const float4*)&f3[i];
      acc0 += a0.x*w0 + a0.y*w1 + a0.z*w2 + a0.w*w3;
      acc1 += a1.x*w0 + a1.y*w1 + a1.z*w2 + a1.w*w3;
      acc2 += a2.x*w0 + a2.y*w1 + a2.z*w2 + a2.w*w3;
      acc3 += a3.x*w0 + a3.y*w1 + a3.z*w2 + a3.w*w3;
    }
    o1s[gq*4+0][j] = acc0;
    o1s[gq*4+1][j] = acc1;
    o1s[gq*4+2][j] = acc2;
    o1s[gq*4+3][j] = acc3;
  }
  __syncthreads();
  {
    int g = tid >> 5, jj = tid & 31;
    float s = 0.f;
    #pragma unroll
    for(int q=0;q<4;q++){
      int j = jj + 32*q;
      float r = fmaxf(o1s[g][j] + l1b[j], 0.f);
      s += r * l2W[j];
    }
    #pragma unroll
    for(int off=16; off>0; off>>=1) s += __shfl_xor(s, off);
    if(jj == 0) out[bG*8 + g] = s + l2b[0];
  }
}

// ---------------- launch ----------------
extern "C" void kernel_launch(void* const* d_in, const int* in_sizes, int n_in,
                              void* d_out, int out_size, void* d_ws, size_t ws_size,
                              hipStream_t stream){
  (void)n_in; (void)out_size; (void)ws_size;
  const int*   z1    = (const int*)  d_in[0];
  const int*   z2    = (const int*)  d_in[1];
  const int*   w     = (const int*)  d_in[2];
  const int*   eidx  = (const int*)  d_in[3];
  const float* ew    = (const float*)d_in[5];
  const float* embw  = (const float*)d_in[6];
  const float* embz1 = (const float*)d_in[7];
  const float* embz2 = (const float*)d_in[8];
  const float* W0    = (const float*)d_in[9];
  const float* b0    = (const float*)d_in[10];
  const float* W1    = (const float*)d_in[11];
  const float* b1    = (const float*)d_in[12];
  const float* W2    = (const float*)d_in[13];
  const float* b2    = (const float*)d_in[14];
  const float* W3    = (const float*)d_in[15];
  const float* b3    = (const float*)d_in[16];
  const float* c1W   = (const float*)d_in[17];
  const float* c1b   = (const float*)d_in[18];
  const float* c2W   = (const float*)d_in[19];
  const float* c2b   = (const float*)d_in[20];
  const float* l1W   = (const float*)d_in[21];
  const float* l1b   = (const float*)d_in[22];
  const float* l2W   = (const float*)d_in[23];
  const float* l2b   = (const float*)d_in[24];
  float* out = (float*)d_out;

  int N = in_sizes[0];
  int E = in_sizes[3]/2;
  int B = N/NPG;
  const int* src = eidx;
  const int* dst = eidx + E;

  char* p = (char*)d_ws;
  auto alloc = [&](size_t bytes)->char*{
    char* r = p;
    p += (bytes + 255) & ~(size_t)255;
    return r;
  };
  float* h1    = (float*)alloc((size_t)N*32*4);
  float* h2    = (float*)alloc((size_t)N*32*4);
  float* h3    = (float*)alloc((size_t)N*32*4);
  float* gv    = (float*)alloc((size_t)N*4);
  float* gx    = (float*)alloc((size_t)N*32*4);
  float* dis   = (float*)alloc((size_t)N*4);
  int*   rs    = (int*)  alloc((size_t)(N+1)*4);
  int*   histT = (int*)  alloc((size_t)NBLKA*NC*4);
  int*   prefA = (int*)  alloc((size_t)NC*NBLKA*4);
  int*   totalA= (int*)  alloc((size_t)NC*4);
  int*   cbase = (int*)  alloc((size_t)(NC+1)*4);
  int2*  csr   = (int2*) alloc((size_t)E*8);
  float* t2G   = (float*)alloc((size_t)B*480*4);
  int2*  ebufA = (int2*)h1;    // alias: dead before h1 written

  int cpb = (E + NBLKA - 1)/NBLKA;
  k_histA   <<<NBLKA, 256, 0, stream>>>(dst, histT, E, cpb);
  k_colscanA<<<NC, NBLKA, 0, stream>>>(histT, prefA, totalA);
  k_bscanA  <<<1,    256, 0, stream>>>(totalA, cbase);
  k_scatterA<<<NBLKA, 256, 0, stream>>>(src, dst, ew, prefA, cbase, ebufA, E, cpb);
  k_bucket8 <<<NC,  1024, 0, stream>>>(ebufA, cbase, dis, rs, csr, N);

  int gG = (N+127)/128;
  int gA = (N+3)/4;
  k_gemm1 <<<gG, 256, 0, stream>>>(w, z1, z2, embw, embz1, embz2, W0, dis, gx, N);
  k_agg32 <<<gA, 256, 0, stream>>>(gx, dis, rs, csr, b0, h1, N);
  k_gemm32<<<gG, 256, 0, stream>>>(h1, W1, dis, gx, N);
  k_agg32 <<<gA, 256, 0, stream>>>(gx, dis, rs, csr, b1, h2, N);
  k_gemm32<<<gG, 256, 0, stream>>>(h2, W2, dis, gx, N);
  k_agg32v<<<gA, 256, 0, stream>>>(gx, dis, rs, csr, b2, W3, h3, gv, N);

  k_sortpool<<<B, 256, 0, stream>>>(gv, dis, rs, csr, b3, h1, h2, h3, c1W, c1b, t2G, N);
  k_tail    <<<B/8, 256, 0, stream>>>(t2G, c2W, c2b, l1W, l1b, l2W, l2b, out);
}